// Round 13
// baseline (1807.167 us; speedup 1.0000x reference)
//
#include <hip/hip_runtime.h>
#include <math.h>

#define DD 512
#define NBLKA 400

#define PM 128          // prefilter tile rows
#define PN 128          // prefilter tile cols
#define KB 32           // k-chunk (one MFMA K per chunk)
#define NCHUNK (DD/KB)  // 16
#define CSPLIT 12       // column splits -> 960 blocks (~3.75/CU)
#define NC 16           // candidates kept per row per split
#define PBUF 16         // push buffer per row
#define NCTOT (CSPLIT*NC)   // 192 candidates per row total
#define KOUTMAX 16
#define RS_MARGIN 2e-4f     // rescore prune margin (bf16 score err bound ~3e-5)

typedef __attribute__((ext_vector_type(8))) short bf16x8;   // 8 bf16 = 4 VGPR
typedef __attribute__((ext_vector_type(4))) float f32x4;    // MFMA 16x16 accumulator

static __device__ __forceinline__ unsigned short f2bf(float f) {
    unsigned u = __float_as_uint(f);
    u += 0x7fff + ((u >> 16) & 1);      // round-to-nearest-even
    return (unsigned short)(u >> 16);
}

// ---------------- Kernel A1: partial column sums of x^2 (fp64, deterministic) ----------------
__global__ void colsum_partial(const float* __restrict__ x, double* __restrict__ partial,
                               int N, int rows_per_block) {
    int b = blockIdx.x;
    int t = threadIdx.x;
    int r0 = b * rows_per_block;
    int r1 = min(r0 + rows_per_block, N);
    double s0 = 0.0, s1 = 0.0;
    for (int r = r0; r < r1; ++r) {
        float v0 = x[(size_t)r * DD + t];
        float v1 = x[(size_t)r * DD + t + 256];
        s0 += (double)v0 * (double)v0;
        s1 += (double)v1 * (double)v1;
    }
    partial[(size_t)b * DD + t]       = s0;
    partial[(size_t)b * DD + t + 256] = s1;
}

// ---------------- Kernel A2: rn=1/max(sqrt(s),eps) fp64, w=rn*rn fp64 ----------------
__global__ void colnorm_finish(const double* __restrict__ partial, double* __restrict__ rn,
                               double* __restrict__ w, int nblk) {
    int c = threadIdx.x;                 // 512 threads
    double s = 0.0;
    for (int b = 0; b < nblk; ++b) s += partial[(size_t)b * DD + c];
    double n = fmax(sqrt(s), 1e-12);
    double r = 1.0 / n;
    rn[c]  = r;
    w[c]   = r * r;
}

// ---------------- Kernel B: sq[i] fp64, sqf[i] fp32, xnbf[i][:] bf16 ----------------
__global__ void row_sq(const float* __restrict__ x, const double* __restrict__ rn,
                       double* __restrict__ sq, float* __restrict__ sqf,
                       unsigned short* __restrict__ xnbf, int N) {
    int i = blockIdx.x;
    int t = threadIdx.x;
    double a0 = (double)x[(size_t)i * DD + t]       * rn[t];
    double a1 = (double)x[(size_t)i * DD + t + 256] * rn[t + 256];
    xnbf[(size_t)i * DD + t]       = f2bf((float)a0);
    xnbf[(size_t)i * DD + t + 256] = f2bf((float)a1);
    double local = a0 * a0 + a1 * a1;
    __shared__ double red[256];
    red[t] = local;
    __syncthreads();
    for (int off = 128; off > 0; off >>= 1) {
        if (t < off) red[t] += red[t + off];
        __syncthreads();
    }
    if (t == 0) { sq[i] = red[0]; sqf[i] = (float)red[0]; }
}

// ---------------- Kernel C: LDS-free bf16 MFMA prefilter ----------------
// Barrier-free K-loop, direct global fragment loads. Single-buffered frags:
// the fully-unrolled body lets the compiler pipeline loads across chunks
// within the register budget (no spill). launch_bounds(256,3): 3 blocks/CU.
__global__ __launch_bounds__(256, 3) void gemm_prefilter(
    const unsigned short* __restrict__ xnbf,
    const float* __restrict__ sqf, int* __restrict__ cand, float* __restrict__ cands,
    int N, int ntileM, int ntileN)
{
    __shared__ float Ls[PM][NC + 1];              // 8704 B
    __shared__ int   Li[PM][NC + 1];              // 8704 B
    __shared__ float Bsc[PM][PBUF + 1];           // 8704 B
    __shared__ int   Bid[PM][PBUF + 1];           // 8704 B
    __shared__ float sqi_s[PM];
    __shared__ float sqj_s[PN];
    __shared__ float thr_s[PM];
    __shared__ int   cnt_s[PM];
    __shared__ int   flag_s;                      // ~37.4 KB

    const int bid   = blockIdx.x;
    const int q     = bid & 7;
    const int s     = bid >> 3;
    const int ridx  = s / CSPLIT;
    const int split = s - ridx * CSPLIT;
    const int rowb  = q + 8 * ridx;
    if (rowb >= ntileM) return;                   // uniform early exit (pad blocks)
    const int row0  = rowb * PM;

    const int t      = threadIdx.x;
    const int lane15 = t & 15;
    const int quad   = (t >> 4) & 3;
    const int wave   = t >> 6;
    const int wr     = (wave >> 1) * 64;
    const int wc     = (wave & 1) * 64;

    if (t == 0) flag_s = 0;
    if (t < PM) {
        int i = row0 + t;
        sqi_s[t] = (i < N) ? sqf[i] : 0.f;
        thr_s[t] = __builtin_inff();
        cnt_s[t] = 0;
        for (int m = 0; m < NC; ++m) { Ls[t][m] = __builtin_inff(); Li[t][m] = 0x7fffffff; }
    }

    // A fragment base pointers (fixed per block)
    const unsigned short* Ap[4];
#pragma unroll
    for (int mt = 0; mt < 4; ++mt)
        Ap[mt] = xnbf + (size_t)(row0 + wr + mt * 16 + lane15) * DD + quad * 8;

    f32x4 acc[4][4];

    for (int tile = split; tile < ntileN; tile += CSPLIT) {
        int col0 = tile * PN;
        const unsigned short* Bp[4];
#pragma unroll
        for (int nt = 0; nt < 4; ++nt)
            Bp[nt] = xnbf + (size_t)(col0 + wc + nt * 16 + lane15) * DD + quad * 8;

        if (t < PN) {
            int j = col0 + t;
            sqj_s[t] = (j < N) ? sqf[j] : __builtin_inff();
        }
        __syncthreads();                 // sqj_s visible before epilogue reads

#pragma unroll
        for (int mt = 0; mt < 4; ++mt)
#pragma unroll
            for (int nt = 0; nt < 4; ++nt)
                acc[mt][nt] = (f32x4){0.f, 0.f, 0.f, 0.f};

        // barrier-free K-loop: single-buffered frags, compiler-pipelined
#pragma unroll
        for (int kcnt = 0; kcnt < NCHUNK; ++kcnt) {
            const int off = kcnt * KB;
            bf16x8 af[4], bf[4];
#pragma unroll
            for (int p = 0; p < 4; ++p) {
                af[p] = *(const bf16x8*)(Ap[p] + off);
                bf[p] = *(const bf16x8*)(Bp[p] + off);
            }
#pragma unroll
            for (int mt = 0; mt < 4; ++mt)
#pragma unroll
                for (int nt = 0; nt < 4; ++nt)
                    acc[mt][nt] = __builtin_amdgcn_mfma_f32_16x16x32_bf16(
                        af[mt], bf[nt], acc[mt][nt], 0, 0, 0);
        }
        // epilogue: scores in place  s = (sq_i - 2g) + sq_j
#pragma unroll
        for (int mt = 0; mt < 4; ++mt)
#pragma unroll
            for (int nt = 0; nt < 4; ++nt)
#pragma unroll
                for (int reg = 0; reg < 4; ++reg) {
                    int rl = wr + mt * 16 + quad * 4 + reg;
                    int cl = wc + nt * 16 + lane15;
                    float g = acc[mt][nt][reg];
                    acc[mt][nt][reg] = (sqi_s[rl] - 2.f * g) + sqj_s[cl];
                }

        // push/merge rounds (race-free 4-barrier protocol, static acc indexing)
        bool tile_edge = (col0 + PN > N);
        unsigned long long done = 0ull;
        for (;;) {
#pragma unroll
            for (int mt = 0; mt < 4; ++mt)
#pragma unroll
                for (int reg = 0; reg < 4; ++reg) {
                    const unsigned long long gb =
                        (0x1111ull << reg) << (mt * 16);
                    int rl = wr + mt * 16 + quad * 4 + reg;
                    float th = thr_s[rl];
                    float gmin = fminf(fminf(acc[mt][0][reg], acc[mt][1][reg]),
                                       fminf(acc[mt][2][reg], acc[mt][3][reg]));
                    if (!tile_edge && gmin > th) { done |= gb; continue; }
                    if ((done & gb) == gb) continue;
#pragma unroll
                    for (int nt = 0; nt < 4; ++nt) {
                        const unsigned long long bit = 1ull << (mt * 16 + nt * 4 + reg);
                        if (!(done & bit)) {
                            float sv = acc[mt][nt][reg];
                            int   j  = col0 + wc + nt * 16 + lane15;
                            if (j < N && sv <= th) {
                                int pos = atomicAdd(&cnt_s[rl], 1);
                                if (pos < PBUF) {
                                    Bsc[rl][pos] = sv;
                                    Bid[rl][pos] = j;
                                    done |= bit;
                                }
                            } else {
                                done |= bit;
                            }
                        }
                    }
                }
            if (done != ~0ull) flag_s = 1;
            __syncthreads();                 // B1
            if (t < PM) {
                int c = cnt_s[t];
                if (c > PBUF) c = PBUF;
                cnt_s[t] = 0;
                for (int m = 0; m < c; ++m) {
                    float sv = Bsc[t][m];
                    int   j  = Bid[t][m];
                    float ws = Ls[t][NC - 1]; int wj = Li[t][NC - 1];
                    if (sv < ws || (sv == ws && j < wj)) {
                        int pos = NC - 1;
                        while (pos > 0) {
                            float ps = Ls[t][pos - 1]; int pj = Li[t][pos - 1];
                            if (!(sv < ps || (sv == ps && j < pj))) break;
                            Ls[t][pos] = ps; Li[t][pos] = pj;
                            --pos;
                        }
                        Ls[t][pos] = sv; Li[t][pos] = j;
                    }
                }
                thr_s[t] = Ls[t][NC - 1];
            }
            __syncthreads();                 // B2
            int go = flag_s;
            __syncthreads();                 // B3
            if (t == 0) flag_s = 0;
            __syncthreads();                 // B4
            if (!go) break;
        }
    }
    // write this split's candidates (index + bf16 score)
    if (t < PM) {
        int i = row0 + t;
        if (i < N) {
            for (int m = 0; m < NC; ++m) {
                cand [(size_t)i * NCTOT + split * NC + m] = Li[t][m];
                cands[(size_t)i * NCTOT + split * NC + m] = Ls[t][m];
            }
        }
    }
}

// ---------------- Kernel D: pruned exact fp64 rescore + top-k ----------------
__global__ __launch_bounds__(256) void rescore_topk(
    const float* __restrict__ x, const double* __restrict__ w,
    const double* __restrict__ sq, const int* __restrict__ cand,
    const float* __restrict__ cands, int* __restrict__ out, int N, int k)
{
    __shared__ float Ssc[4][NCTOT];
    int lane = threadIdx.x & 63;
    int wid  = threadIdx.x >> 6;
    int i = blockIdx.x * 4 + wid;
    if (i >= N) return;

    size_t base = (size_t)i * NCTOT;
#pragma unroll
    for (int z = 0; z < NCTOT / 64; ++z)
        Ssc[wid][lane + z * 64] = cands[base + lane + z * 64];

    // 9th-smallest via pivot counting: 3 pivots/lane cover all 192 slots
    float p0 = Ssc[wid][lane * 3 + 0];
    float p1 = Ssc[wid][lane * 3 + 1];
    float p2 = Ssc[wid][lane * 3 + 2];
    int c0 = 0, c1 = 0, c2 = 0;
    for (int m = 0; m < NCTOT; ++m) {
        float s = Ssc[wid][m];
        c0 += (s <= p0); c1 += (s <= p1); c2 += (s <= p2);
    }
    float best = __builtin_inff();
    if (c0 >= k) best = p0;
    if (c1 >= k && p1 < best) best = p1;
    if (c2 >= k && p2 < best) best = p2;
#pragma unroll
    for (int off = 32; off > 0; off >>= 1)
        best = fminf(best, __shfl_xor(best, off, 64));
    float cut = best + RS_MARGIN;

    double aw[8];
#pragma unroll
    for (int c = 0; c < 8; ++c) {
        int d = lane + 64 * c;
        aw[c] = (double)x[(size_t)i * DD + d] * w[d];
    }
    double sqi = sq[i];

    double bs[KOUTMAX];
    int    bj[KOUTMAX];
    for (int r = 0; r < k; ++r) { bs[r] = __builtin_inf(); bj[r] = 0x7fffffff; }

    int pend = -1;                    // wave-uniform pending candidate index j
    for (int m = 0; m <= NCTOT; ++m) {
        int j1cand = -1;
        if (m < NCTOT) {
            if (Ssc[wid][m] > cut) continue;          // wave-uniform skip
            j1cand = cand[base + m];
            if (pend < 0) { pend = j1cand; continue; } // buffer first of a pair
        } else if (pend < 0) {
            break;                                     // nothing left
        }
        int j0 = pend, j1 = j1cand;
        pend = -1;
        const float* q0 = &x[(size_t)j0 * DD + lane];
        const float* q1 = (j1 >= 0) ? &x[(size_t)j1 * DD + lane] : q0;
        float v0[8], v1[8];
#pragma unroll
        for (int c = 0; c < 8; ++c) v0[c] = q0[64 * c];
#pragma unroll
        for (int c = 0; c < 8; ++c) v1[c] = q1[64 * c];
        double d0 = 0.0, d1 = 0.0;
#pragma unroll
        for (int c = 0; c < 8; ++c) d0 = fma(aw[c], (double)v0[c], d0);
#pragma unroll
        for (int c = 0; c < 8; ++c) d1 = fma(aw[c], (double)v1[c], d1);
#pragma unroll
        for (int off = 32; off > 0; off >>= 1) {
            d0 += __shfl_xor(d0, off, 64);
            d1 += __shfl_xor(d1, off, 64);
        }
        double s0 = (sqi - 2.0 * d0) + sq[j0];
        double s1 = (j1 >= 0) ? (sqi - 2.0 * d1) + sq[j1] : __builtin_inf();
#pragma unroll 1
        for (int pick = 0; pick < 2; ++pick) {
            double sv = pick ? s1 : s0;
            int    j  = pick ? j1 : j0;
            if (j < 0) continue;
            if (sv < bs[k - 1] || (sv == bs[k - 1] && j < bj[k - 1])) {
                int pos = k - 1;
                while (pos > 0) {
                    double ps = bs[pos - 1]; int pj = bj[pos - 1];
                    if (!(sv < ps || (sv == ps && j < pj))) break;
                    bs[pos] = ps; bj[pos] = pj;
                    --pos;
                }
                bs[pos] = sv; bj[pos] = j;
            }
        }
    }
    if (lane == 0) {
        for (int r = 0; r < k; ++r) {
            out[(size_t)i * k + r]                 = bj[r];
            out[(size_t)N * k + (size_t)i * k + r] = i;
        }
    }
}

extern "C" void kernel_launch(void* const* d_in, const int* in_sizes, int n_in,
                              void* d_out, int out_size, void* d_ws, size_t ws_size,
                              hipStream_t stream) {
    const float* x = (const float*)d_in[0];
    int N = in_sizes[0] / DD;            // 10000
    int k = out_size / (2 * N);          // 9
    if (k > KOUTMAX) k = KOUTMAX;

    char* ws = (char*)d_ws;
    double*         partial = (double*)ws;                       // 400*512*8 = 1638400 B
    double*         rn      = (double*)(ws + 1638400);           // 4096 B
    double*         w       = (double*)(ws + 1642496);           // 4096 B
    double*         sq      = (double*)(ws + 1646592);           // 80000 B
    float*          sqf     = (float*) (ws + 1726592);           // 40000 B
    unsigned short* xnbf    = (unsigned short*)(ws + 1766592);   // N*512*2 = 10.24 MB
    int*            cand    = (int*)   (ws + 12006592);          // N*192*4 = 7.68 MB
    float*          cands   = (float*) (ws + 19686592);          // N*192*4 = 7.68 MB

    int rpb = (N + NBLKA - 1) / NBLKA;
    hipLaunchKernelGGL(colsum_partial, dim3(NBLKA), dim3(256), 0, stream, x, partial, N, rpb);
    hipLaunchKernelGGL(colnorm_finish, dim3(1), dim3(512), 0, stream, partial, rn, w, NBLKA);
    hipLaunchKernelGGL(row_sq, dim3(N), dim3(256), 0, stream, x, rn, sq, sqf, xnbf, N);

    int ntileM = (N + PM - 1) / PM;      // 79
    int ntileN = (N + PN - 1) / PN;      // 79
    int rows_per_xcd = (ntileM + 7) / 8; // 10
    int nblk = 8 * rows_per_xcd * CSPLIT; // 960 (pad blocks exit early)
    hipLaunchKernelGGL(gemm_prefilter, dim3(nblk), dim3(256), 0, stream,
                       xnbf, sqf, cand, cands, N, ntileM, ntileN);

    hipLaunchKernelGGL(rescore_topk, dim3((N + 3) / 4), dim3(256), 0, stream,
                       x, w, sq, cand, cands, (int*)d_out, N, k);
}

// Round 14
// 1080.551 us; speedup vs baseline: 1.6724x; 1.6724x over previous
//
#include <hip/hip_runtime.h>
#include <math.h>

#define DD 512
#define NBLKA 400

#define PM 128          // prefilter tile rows
#define PN 128          // prefilter tile cols
#define KB 32           // k-chunk (one MFMA K per chunk)
#define CSPLIT 8        // column splits -> 640 blocks (~2.5/CU, 3 resident fit)
#define NC 16           // candidates kept per row per split
#define PBUF 16         // push buffer per row
#define NCTOT (CSPLIT*NC)   // 128 candidates per row total
#define KOUTMAX 16
#define RS_MARGIN 2e-4f     // rescore prune margin (bf16 score err bound ~3e-5)

typedef __attribute__((ext_vector_type(8))) short bf16x8;   // 8 bf16 = 4 VGPR
typedef __attribute__((ext_vector_type(4))) float f32x4;    // MFMA 16x16 accumulator

static __device__ __forceinline__ unsigned short f2bf(float f) {
    unsigned u = __float_as_uint(f);
    u += 0x7fff + ((u >> 16) & 1);      // round-to-nearest-even
    return (unsigned short)(u >> 16);
}

// ---------------- Kernel A1: partial column sums of x^2 (fp64, deterministic) ----------------
__global__ void colsum_partial(const float* __restrict__ x, double* __restrict__ partial,
                               int N, int rows_per_block) {
    int b = blockIdx.x;
    int t = threadIdx.x;
    int r0 = b * rows_per_block;
    int r1 = min(r0 + rows_per_block, N);
    double s0 = 0.0, s1 = 0.0;
    for (int r = r0; r < r1; ++r) {
        float v0 = x[(size_t)r * DD + t];
        float v1 = x[(size_t)r * DD + t + 256];
        s0 += (double)v0 * (double)v0;
        s1 += (double)v1 * (double)v1;
    }
    partial[(size_t)b * DD + t]       = s0;
    partial[(size_t)b * DD + t + 256] = s1;
}

// ---------------- Kernel A2: rn=1/max(sqrt(s),eps) fp64, w=rn*rn fp64 ----------------
__global__ void colnorm_finish(const double* __restrict__ partial, double* __restrict__ rn,
                               double* __restrict__ w, int nblk) {
    int c = threadIdx.x;                 // 512 threads
    double s = 0.0;
    for (int b = 0; b < nblk; ++b) s += partial[(size_t)b * DD + c];
    double n = fmax(sqrt(s), 1e-12);
    double r = 1.0 / n;
    rn[c]  = r;
    w[c]   = r * r;
}

// ---------------- Kernel B: sq[i] fp64, sqf[i] fp32, xnbf[i][:] bf16 ----------------
__global__ void row_sq(const float* __restrict__ x, const double* __restrict__ rn,
                       double* __restrict__ sq, float* __restrict__ sqf,
                       unsigned short* __restrict__ xnbf, int N) {
    int i = blockIdx.x;
    int t = threadIdx.x;
    double a0 = (double)x[(size_t)i * DD + t]       * rn[t];
    double a1 = (double)x[(size_t)i * DD + t + 256] * rn[t + 256];
    xnbf[(size_t)i * DD + t]       = f2bf((float)a0);
    xnbf[(size_t)i * DD + t + 256] = f2bf((float)a1);
    double local = a0 * a0 + a1 * a1;
    __shared__ double red[256];
    red[t] = local;
    __syncthreads();
    for (int off = 128; off > 0; off >>= 1) {
        if (t < off) red[t] += red[t + off];
        __syncthreads();
    }
    if (t == 0) { sq[i] = red[0]; sqf[i] = (float)red[0]; }
}

// ---------------- Kernel C: m97-style bf16 MFMA prefilter + per-row top-16 ----------------
// global_load_lds width=16 DMA staging into UNPADDED A_s/B_s (layout is
// wave-uniform base + lane*16 -> 16 consecutive rows x 64B per wave-instr).
// 2-barrier K-loop; fragments via ds_read_b128.
__global__ __launch_bounds__(256, 3) void gemm_prefilter(
    const unsigned short* __restrict__ xnbf,
    const float* __restrict__ sqf, int* __restrict__ cand, float* __restrict__ cands,
    int N, int ntileM, int ntileN)
{
    __shared__ unsigned short A_s[PM][KB];        // 8192 B, unpadded (DMA layout)
    __shared__ unsigned short B_s[PN][KB];        // 8192 B
    __shared__ float Ls[PM][NC + 1];              // 8704 B
    __shared__ int   Li[PM][NC + 1];              // 8704 B
    __shared__ float Bsc[PM][PBUF + 1];           // 8704 B
    __shared__ int   Bid[PM][PBUF + 1];           // 8704 B
    __shared__ float sqi_s[PM];
    __shared__ float sqj_s[PN];
    __shared__ float thr_s[PM];
    __shared__ int   cnt_s[PM];
    __shared__ int   flag_s;                      // ~53.3 KB -> 3 blocks/CU

    const int bid   = blockIdx.x;
    const int q     = bid & 7;
    const int s     = bid >> 3;
    const int ridx  = s / CSPLIT;
    const int split = s - ridx * CSPLIT;
    const int rowb  = q + 8 * ridx;
    if (rowb >= ntileM) return;                   // uniform early exit (pad blocks)
    const int row0  = rowb * PM;

    const int t      = threadIdx.x;
    const int lane15 = t & 15;
    const int quad   = (t >> 4) & 3;
    const int wave   = t >> 6;
    const int wr     = (wave >> 1) * 64;
    const int wc     = (wave & 1) * 64;

    // staging geometry: thread t handles rows (t>>2) and (t>>2)+64, 16B chunk t&3.
    // Per wave-instr: 16 consecutive rows x 64B -> contiguous 1KB = lane*16 order.
    const int sr  = t >> 2;
    const int scs = (t & 3) * 8;                  // short offset within 32-short row
    const size_t gA0 = (size_t)(row0 + sr) * DD + scs;
    const size_t gA1 = (size_t)(row0 + sr + 64) * DD + scs;
    unsigned short* lA0 = &A_s[sr][scs];
    unsigned short* lA1 = &A_s[sr + 64][scs];
    unsigned short* lB0 = &B_s[sr][scs];
    unsigned short* lB1 = &B_s[sr + 64][scs];

    if (t == 0) flag_s = 0;
    if (t < PM) {
        int i = row0 + t;
        sqi_s[t] = (i < N) ? sqf[i] : 0.f;
        thr_s[t] = __builtin_inff();
        cnt_s[t] = 0;
        for (int m = 0; m < NC; ++m) { Ls[t][m] = __builtin_inff(); Li[t][m] = 0x7fffffff; }
    }

    f32x4 acc[4][4];

    for (int tile = split; tile < ntileN; tile += CSPLIT) {
        int col0 = tile * PN;
        const size_t gB0 = (size_t)(col0 + sr) * DD + scs;
        const size_t gB1 = gB0 + (size_t)64 * DD;

        if (t < PN) {
            int j = col0 + t;
            sqj_s[t] = (j < N) ? sqf[j] : __builtin_inff();
        }
#pragma unroll
        for (int mt = 0; mt < 4; ++mt)
#pragma unroll
            for (int nt = 0; nt < 4; ++nt)
                acc[mt][nt] = (f32x4){0.f, 0.f, 0.f, 0.f};

#pragma unroll 1
        for (int kc = 0; kc < DD; kc += KB) {
            // DMA this chunk straight into LDS (no VGPR round-trip)
            __builtin_amdgcn_global_load_lds((const unsigned int*)(xnbf + gA0 + kc),
                                             (unsigned int*)lA0, 16, 0, 0);
            __builtin_amdgcn_global_load_lds((const unsigned int*)(xnbf + gA1 + kc),
                                             (unsigned int*)lA1, 16, 0, 0);
            __builtin_amdgcn_global_load_lds((const unsigned int*)(xnbf + gB0 + kc),
                                             (unsigned int*)lB0, 16, 0, 0);
            __builtin_amdgcn_global_load_lds((const unsigned int*)(xnbf + gB1 + kc),
                                             (unsigned int*)lB1, 16, 0, 0);
            __syncthreads();   // drain DMA (vmcnt) -> staged data visible
            bf16x8 af[4], bfg[4];
#pragma unroll
            for (int mt = 0; mt < 4; ++mt)
                af[mt] = *(const bf16x8*)&A_s[wr + mt * 16 + lane15][quad * 8];
#pragma unroll
            for (int nt = 0; nt < 4; ++nt)
                bfg[nt] = *(const bf16x8*)&B_s[wc + nt * 16 + lane15][quad * 8];
#pragma unroll
            for (int mt = 0; mt < 4; ++mt)
#pragma unroll
                for (int nt = 0; nt < 4; ++nt)
                    acc[mt][nt] = __builtin_amdgcn_mfma_f32_16x16x32_bf16(
                        af[mt], bfg[nt], acc[mt][nt], 0, 0, 0);
            __syncthreads();   // frag reads done before next chunk's DMA overwrites
        }
        // epilogue: scores in place  s = (sq_i - 2g) + sq_j
#pragma unroll
        for (int mt = 0; mt < 4; ++mt)
#pragma unroll
            for (int nt = 0; nt < 4; ++nt)
#pragma unroll
                for (int reg = 0; reg < 4; ++reg) {
                    int rl = wr + mt * 16 + quad * 4 + reg;
                    int cl = wc + nt * 16 + lane15;
                    float g = acc[mt][nt][reg];
                    acc[mt][nt][reg] = (sqi_s[rl] - 2.f * g) + sqj_s[cl];
                }

        // push/merge rounds (race-free 4-barrier protocol, static acc indexing)
        bool tile_edge = (col0 + PN > N);
        unsigned long long done = 0ull;
        for (;;) {
#pragma unroll
            for (int mt = 0; mt < 4; ++mt)
#pragma unroll
                for (int reg = 0; reg < 4; ++reg) {
                    const unsigned long long gb =
                        (0x1111ull << reg) << (mt * 16);
                    int rl = wr + mt * 16 + quad * 4 + reg;
                    float th = thr_s[rl];
                    float gmin = fminf(fminf(acc[mt][0][reg], acc[mt][1][reg]),
                                       fminf(acc[mt][2][reg], acc[mt][3][reg]));
                    if (!tile_edge && gmin > th) { done |= gb; continue; }
                    if ((done & gb) == gb) continue;
#pragma unroll
                    for (int nt = 0; nt < 4; ++nt) {
                        const unsigned long long bit = 1ull << (mt * 16 + nt * 4 + reg);
                        if (!(done & bit)) {
                            float sv = acc[mt][nt][reg];
                            int   j  = col0 + wc + nt * 16 + lane15;
                            if (j < N && sv <= th) {
                                int pos = atomicAdd(&cnt_s[rl], 1);
                                if (pos < PBUF) {
                                    Bsc[rl][pos] = sv;
                                    Bid[rl][pos] = j;
                                    done |= bit;
                                }
                            } else {
                                done |= bit;
                            }
                        }
                    }
                }
            if (done != ~0ull) flag_s = 1;
            __syncthreads();                 // B1
            if (t < PM) {
                int c = cnt_s[t];
                if (c > PBUF) c = PBUF;
                cnt_s[t] = 0;
                for (int m = 0; m < c; ++m) {
                    float sv = Bsc[t][m];
                    int   j  = Bid[t][m];
                    float ws = Ls[t][NC - 1]; int wj = Li[t][NC - 1];
                    if (sv < ws || (sv == ws && j < wj)) {
                        int pos = NC - 1;
                        while (pos > 0) {
                            float ps = Ls[t][pos - 1]; int pj = Li[t][pos - 1];
                            if (!(sv < ps || (sv == ps && j < pj))) break;
                            Ls[t][pos] = ps; Li[t][pos] = pj;
                            --pos;
                        }
                        Ls[t][pos] = sv; Li[t][pos] = j;
                    }
                }
                thr_s[t] = Ls[t][NC - 1];
            }
            __syncthreads();                 // B2
            int go = flag_s;
            __syncthreads();                 // B3
            if (t == 0) flag_s = 0;
            __syncthreads();                 // B4
            if (!go) break;
        }
    }
    // write this split's candidates (index + bf16 score)
    if (t < PM) {
        int i = row0 + t;
        if (i < N) {
            for (int m = 0; m < NC; ++m) {
                cand [(size_t)i * NCTOT + split * NC + m] = Li[t][m];
                cands[(size_t)i * NCTOT + split * NC + m] = Ls[t][m];
            }
        }
    }
}

// ---------------- Kernel D: pruned exact fp64 rescore + top-k ----------------
// One wave per row; prune via 9th-smallest bf16 score; dual-candidate
// pipelining (prune test is wave-uniform -> pairing is divergence-free).
__global__ __launch_bounds__(256) void rescore_topk(
    const float* __restrict__ x, const double* __restrict__ w,
    const double* __restrict__ sq, const int* __restrict__ cand,
    const float* __restrict__ cands, int* __restrict__ out, int N, int k)
{
    __shared__ float Ssc[4][NCTOT];
    int lane = threadIdx.x & 63;
    int wid  = threadIdx.x >> 6;
    int i = blockIdx.x * 4 + wid;
    if (i >= N) return;

    size_t base = (size_t)i * NCTOT;
#pragma unroll
    for (int z = 0; z < NCTOT / 64; ++z)
        Ssc[wid][lane + z * 64] = cands[base + lane + z * 64];

    // 9th-smallest via pivot counting: 2 pivots/lane cover all 128 slots
    float p0 = Ssc[wid][lane * 2 + 0];
    float p1 = Ssc[wid][lane * 2 + 1];
    int c0 = 0, c1 = 0;
    for (int m = 0; m < NCTOT; ++m) {
        float s = Ssc[wid][m];
        c0 += (s <= p0); c1 += (s <= p1);
    }
    float best = __builtin_inff();
    if (c0 >= k) best = p0;
    if (c1 >= k && p1 < best) best = p1;
#pragma unroll
    for (int off = 32; off > 0; off >>= 1)
        best = fminf(best, __shfl_xor(best, off, 64));
    float cut = best + RS_MARGIN;

    double aw[8];
#pragma unroll
    for (int c = 0; c < 8; ++c) {
        int d = lane + 64 * c;
        aw[c] = (double)x[(size_t)i * DD + d] * w[d];
    }
    double sqi = sq[i];

    double bs[KOUTMAX];
    int    bj[KOUTMAX];
    for (int r = 0; r < k; ++r) { bs[r] = __builtin_inf(); bj[r] = 0x7fffffff; }

    int pend = -1;                    // wave-uniform pending candidate index j
    for (int m = 0; m <= NCTOT; ++m) {
        int j1cand = -1;
        if (m < NCTOT) {
            if (Ssc[wid][m] > cut) continue;          // wave-uniform skip
            j1cand = cand[base + m];
            if (pend < 0) { pend = j1cand; continue; } // buffer first of a pair
        } else if (pend < 0) {
            break;                                     // nothing left
        }
        int j0 = pend, j1 = j1cand;
        pend = -1;
        const float* q0 = &x[(size_t)j0 * DD + lane];
        const float* q1 = (j1 >= 0) ? &x[(size_t)j1 * DD + lane] : q0;
        float v0[8], v1[8];
#pragma unroll
        for (int c = 0; c < 8; ++c) v0[c] = q0[64 * c];
#pragma unroll
        for (int c = 0; c < 8; ++c) v1[c] = q1[64 * c];
        double d0 = 0.0, d1 = 0.0;
#pragma unroll
        for (int c = 0; c < 8; ++c) d0 = fma(aw[c], (double)v0[c], d0);
#pragma unroll
        for (int c = 0; c < 8; ++c) d1 = fma(aw[c], (double)v1[c], d1);
#pragma unroll
        for (int off = 32; off > 0; off >>= 1) {
            d0 += __shfl_xor(d0, off, 64);
            d1 += __shfl_xor(d1, off, 64);
        }
        double s0 = (sqi - 2.0 * d0) + sq[j0];
        double s1 = (j1 >= 0) ? (sqi - 2.0 * d1) + sq[j1] : __builtin_inf();
#pragma unroll 1
        for (int pick = 0; pick < 2; ++pick) {
            double sv = pick ? s1 : s0;
            int    j  = pick ? j1 : j0;
            if (j < 0) continue;
            if (sv < bs[k - 1] || (sv == bs[k - 1] && j < bj[k - 1])) {
                int pos = k - 1;
                while (pos > 0) {
                    double ps = bs[pos - 1]; int pj = bj[pos - 1];
                    if (!(sv < ps || (sv == ps && j < pj))) break;
                    bs[pos] = ps; bj[pos] = pj;
                    --pos;
                }
                bs[pos] = sv; bj[pos] = j;
            }
        }
    }
    if (lane == 0) {
        for (int r = 0; r < k; ++r) {
            out[(size_t)i * k + r]                 = bj[r];
            out[(size_t)N * k + (size_t)i * k + r] = i;
        }
    }
}

extern "C" void kernel_launch(void* const* d_in, const int* in_sizes, int n_in,
                              void* d_out, int out_size, void* d_ws, size_t ws_size,
                              hipStream_t stream) {
    const float* x = (const float*)d_in[0];
    int N = in_sizes[0] / DD;            // 10000
    int k = out_size / (2 * N);          // 9
    if (k > KOUTMAX) k = KOUTMAX;

    char* ws = (char*)d_ws;
    double*         partial = (double*)ws;                       // 400*512*8 = 1638400 B
    double*         rn      = (double*)(ws + 1638400);           // 4096 B
    double*         w       = (double*)(ws + 1642496);           // 4096 B
    double*         sq      = (double*)(ws + 1646592);           // 80000 B
    float*          sqf     = (float*) (ws + 1726592);           // 40000 B
    unsigned short* xnbf    = (unsigned short*)(ws + 1766592);   // N*512*2 = 10.24 MB
    int*            cand    = (int*)   (ws + 12006592);          // N*128*4 = 5.12 MB
    float*          cands   = (float*) (ws + 17126592);          // N*128*4 = 5.12 MB

    int rpb = (N + NBLKA - 1) / NBLKA;
    hipLaunchKernelGGL(colsum_partial, dim3(NBLKA), dim3(256), 0, stream, x, partial, N, rpb);
    hipLaunchKernelGGL(colnorm_finish, dim3(1), dim3(512), 0, stream, partial, rn, w, NBLKA);
    hipLaunchKernelGGL(row_sq, dim3(N), dim3(256), 0, stream, x, rn, sq, sqf, xnbf, N);

    int ntileM = (N + PM - 1) / PM;      // 79
    int ntileN = (N + PN - 1) / PN;      // 79
    int rows_per_xcd = (ntileM + 7) / 8; // 10
    int nblk = 8 * rows_per_xcd * CSPLIT; // 640 (pad blocks exit early)
    hipLaunchKernelGGL(gemm_prefilter, dim3(nblk), dim3(256), 0, stream,
                       xnbf, sqf, cand, cands, N, ntileM, ntileN);

    hipLaunchKernelGGL(rescore_topk, dim3((N + 3) / 4), dim3(256), 0, stream,
                       x, w, sq, cand, cands, (int*)d_out, N, k);
}

// Round 15
// 939.496 us; speedup vs baseline: 1.9236x; 1.1501x over previous
//
#include <hip/hip_runtime.h>
#include <math.h>

#define DD 512
#define NBLKA 400

#define PM 128          // prefilter tile rows
#define PN 128          // prefilter tile cols
#define KB 64           // k-chunk (two MFMA K-steps per chunk)
#define CSPLIT 6        // column splits -> 480 blocks = exactly 2/CU, no tail
#define NC 12           // candidates kept per row per split (>= k=9)
#define PBUF 8          // push buffer per row
#define NCTOT (CSPLIT*NC)   // 72 candidates per row total
#define KOUTMAX 16
#define RS_MARGIN 2e-4f     // rescore prune margin (bf16 score err bound ~3e-5)

typedef __attribute__((ext_vector_type(8))) short bf16x8;   // 8 bf16 = 4 VGPR
typedef __attribute__((ext_vector_type(4))) float f32x4;    // MFMA 16x16 accumulator

static __device__ __forceinline__ unsigned short f2bf(float f) {
    unsigned u = __float_as_uint(f);
    u += 0x7fff + ((u >> 16) & 1);      // round-to-nearest-even
    return (unsigned short)(u >> 16);
}

// ---------------- Kernel A1: partial column sums of x^2 (fp64, deterministic) ----------------
__global__ void colsum_partial(const float* __restrict__ x, double* __restrict__ partial,
                               int N, int rows_per_block) {
    int b = blockIdx.x;
    int t = threadIdx.x;
    int r0 = b * rows_per_block;
    int r1 = min(r0 + rows_per_block, N);
    double s0 = 0.0, s1 = 0.0;
    for (int r = r0; r < r1; ++r) {
        float v0 = x[(size_t)r * DD + t];
        float v1 = x[(size_t)r * DD + t + 256];
        s0 += (double)v0 * (double)v0;
        s1 += (double)v1 * (double)v1;
    }
    partial[(size_t)b * DD + t]       = s0;
    partial[(size_t)b * DD + t + 256] = s1;
}

// ---------------- Kernel A2: rn=1/max(sqrt(s),eps) fp64, w=rn*rn fp64 ----------------
__global__ void colnorm_finish(const double* __restrict__ partial, double* __restrict__ rn,
                               double* __restrict__ w, int nblk) {
    int c = threadIdx.x;                 // 512 threads
    double s = 0.0;
    for (int b = 0; b < nblk; ++b) s += partial[(size_t)b * DD + c];
    double n = fmax(sqrt(s), 1e-12);
    double r = 1.0 / n;
    rn[c]  = r;
    w[c]   = r * r;
}

// ---------------- Kernel B: sq[i] fp64, sqf[i] fp32, xnbf[i][:] bf16 ----------------
__global__ void row_sq(const float* __restrict__ x, const double* __restrict__ rn,
                       double* __restrict__ sq, float* __restrict__ sqf,
                       unsigned short* __restrict__ xnbf, int N) {
    int i = blockIdx.x;
    int t = threadIdx.x;
    double a0 = (double)x[(size_t)i * DD + t]       * rn[t];
    double a1 = (double)x[(size_t)i * DD + t + 256] * rn[t + 256];
    xnbf[(size_t)i * DD + t]       = f2bf((float)a0);
    xnbf[(size_t)i * DD + t + 256] = f2bf((float)a1);
    double local = a0 * a0 + a1 * a1;
    __shared__ double red[256];
    red[t] = local;
    __syncthreads();
    for (int off = 128; off > 0; off >>= 1) {
        if (t < off) red[t] += red[t + off];
        __syncthreads();
    }
    if (t == 0) { sq[i] = red[0]; sqf[i] = (float)red[0]; }
}

// ---------------- Kernel C: m97-style bf16 MFMA prefilter, BK=64 ----------------
// global_load_lds width=16 DMA into kstep-major A_s[2][128][32] (row stride
// stays 64B -> same conflict profile as BK=32; DMA layout is wave-uniform
// base + lane*16). 8 chunks/tile -> half the vmcnt(0) drain events.
__global__ __launch_bounds__(256, 2) void gemm_prefilter(
    const unsigned short* __restrict__ xnbf,
    const float* __restrict__ sqf, int* __restrict__ cand, float* __restrict__ cands,
    int N, int ntileM, int ntileN)
{
    __shared__ unsigned short A_s[2][PM][32];     // 16384 B
    __shared__ unsigned short B_s[2][PN][32];     // 16384 B
    __shared__ float Ls[PM][NC + 1];              // 6656 B
    __shared__ int   Li[PM][NC + 1];              // 6656 B
    __shared__ float Bsc[PM][PBUF + 1];           // 4608 B
    __shared__ int   Bid[PM][PBUF + 1];           // 4608 B
    __shared__ float sqi_s[PM];
    __shared__ float sqj_s[PN];
    __shared__ float thr_s[PM];
    __shared__ int   cnt_s[PM];
    __shared__ int   flag_s;                      // ~57.2 KB -> 2 blocks/CU

    const int bid   = blockIdx.x;
    const int q     = bid & 7;
    const int s     = bid >> 3;
    const int ridx  = s / CSPLIT;
    const int split = s - ridx * CSPLIT;
    const int rowb  = q + 8 * ridx;
    if (rowb >= ntileM) return;                   // uniform early exit (pad blocks)
    const int row0  = rowb * PM;

    const int t      = threadIdx.x;
    const int lane15 = t & 15;
    const int quad   = (t >> 4) & 3;
    const int wave   = t >> 6;
    const int wr     = (wave >> 1) * 64;
    const int wc     = (wave & 1) * 64;

    if (t == 0) flag_s = 0;
    if (t < PM) {
        int i = row0 + t;
        sqi_s[t] = (i < N) ? sqf[i] : 0.f;
        thr_s[t] = __builtin_inff();
        cnt_s[t] = 0;
        for (int m = 0; m < NC; ++m) { Ls[t][m] = __builtin_inff(); Li[t][m] = 0x7fffffff; }
    }

    f32x4 acc[4][4];

    for (int tile = split; tile < ntileN; tile += CSPLIT) {
        int col0 = tile * PN;

        if (t < PN) {
            int j = col0 + t;
            sqj_s[t] = (j < N) ? sqf[j] : __builtin_inff();
        }
#pragma unroll
        for (int mt = 0; mt < 4; ++mt)
#pragma unroll
            for (int nt = 0; nt < 4; ++nt)
                acc[mt][nt] = (f32x4){0.f, 0.f, 0.f, 0.f};

#pragma unroll 1
        for (int kc = 0; kc < DD; kc += KB) {
            // DMA chunk: A and B, 4 wave-instrs each per thread
#pragma unroll
            for (int l = 0; l < 4; ++l) {
                int e    = t + l * 256;           // 0..1023 (16B chunks)
                int half = e >> 9;                // kstep half
                int re   = e & 511;
                int row  = re >> 2;
                int c    = re & 3;
                size_t gA = (size_t)(row0 + row) * DD + kc + half * 32 + c * 8;
                __builtin_amdgcn_global_load_lds(
                    (const unsigned int*)(xnbf + gA),
                    (unsigned int*)((unsigned short*)A_s + (size_t)e * 8), 16, 0, 0);
                size_t gB = (size_t)(col0 + row) * DD + kc + half * 32 + c * 8;
                __builtin_amdgcn_global_load_lds(
                    (const unsigned int*)(xnbf + gB),
                    (unsigned int*)((unsigned short*)B_s + (size_t)e * 8), 16, 0, 0);
            }
            __syncthreads();   // drain DMA -> staged data visible
#pragma unroll
            for (int ks = 0; ks < 2; ++ks) {
                bf16x8 af[4], bfg[4];
#pragma unroll
                for (int mt = 0; mt < 4; ++mt)
                    af[mt] = *(const bf16x8*)&A_s[ks][wr + mt * 16 + lane15][quad * 8];
#pragma unroll
                for (int nt = 0; nt < 4; ++nt)
                    bfg[nt] = *(const bf16x8*)&B_s[ks][wc + nt * 16 + lane15][quad * 8];
#pragma unroll
                for (int mt = 0; mt < 4; ++mt)
#pragma unroll
                    for (int nt = 0; nt < 4; ++nt)
                        acc[mt][nt] = __builtin_amdgcn_mfma_f32_16x16x32_bf16(
                            af[mt], bfg[nt], acc[mt][nt], 0, 0, 0);
            }
            __syncthreads();   // frag reads done before next chunk's DMA overwrites
        }
        // epilogue: scores in place  s = (sq_i - 2g) + sq_j
#pragma unroll
        for (int mt = 0; mt < 4; ++mt)
#pragma unroll
            for (int nt = 0; nt < 4; ++nt)
#pragma unroll
                for (int reg = 0; reg < 4; ++reg) {
                    int rl = wr + mt * 16 + quad * 4 + reg;
                    int cl = wc + nt * 16 + lane15;
                    float g = acc[mt][nt][reg];
                    acc[mt][nt][reg] = (sqi_s[rl] - 2.f * g) + sqj_s[cl];
                }

        // push/merge rounds (race-free 4-barrier protocol, static acc indexing)
        bool tile_edge = (col0 + PN > N);
        unsigned long long done = 0ull;
        for (;;) {
#pragma unroll
            for (int mt = 0; mt < 4; ++mt)
#pragma unroll
                for (int reg = 0; reg < 4; ++reg) {
                    const unsigned long long gb =
                        (0x1111ull << reg) << (mt * 16);
                    int rl = wr + mt * 16 + quad * 4 + reg;
                    float th = thr_s[rl];
                    float gmin = fminf(fminf(acc[mt][0][reg], acc[mt][1][reg]),
                                       fminf(acc[mt][2][reg], acc[mt][3][reg]));
                    if (!tile_edge && gmin > th) { done |= gb; continue; }
                    if ((done & gb) == gb) continue;
#pragma unroll
                    for (int nt = 0; nt < 4; ++nt) {
                        const unsigned long long bit = 1ull << (mt * 16 + nt * 4 + reg);
                        if (!(done & bit)) {
                            float sv = acc[mt][nt][reg];
                            int   j  = col0 + wc + nt * 16 + lane15;
                            if (j < N && sv <= th) {
                                int pos = atomicAdd(&cnt_s[rl], 1);
                                if (pos < PBUF) {
                                    Bsc[rl][pos] = sv;
                                    Bid[rl][pos] = j;
                                    done |= bit;
                                }
                            } else {
                                done |= bit;
                            }
                        }
                    }
                }
            if (done != ~0ull) flag_s = 1;
            __syncthreads();                 // B1
            if (t < PM) {
                int c = cnt_s[t];
                if (c > PBUF) c = PBUF;
                cnt_s[t] = 0;
                for (int m = 0; m < c; ++m) {
                    float sv = Bsc[t][m];
                    int   j  = Bid[t][m];
                    float ws = Ls[t][NC - 1]; int wj = Li[t][NC - 1];
                    if (sv < ws || (sv == ws && j < wj)) {
                        int pos = NC - 1;
                        while (pos > 0) {
                            float ps = Ls[t][pos - 1]; int pj = Li[t][pos - 1];
                            if (!(sv < ps || (sv == ps && j < pj))) break;
                            Ls[t][pos] = ps; Li[t][pos] = pj;
                            --pos;
                        }
                        Ls[t][pos] = sv; Li[t][pos] = j;
                    }
                }
                thr_s[t] = Ls[t][NC - 1];
            }
            __syncthreads();                 // B2
            int go = flag_s;
            __syncthreads();                 // B3
            if (t == 0) flag_s = 0;
            __syncthreads();                 // B4
            if (!go) break;
        }
    }
    // write this split's candidates (index + bf16 score)
    if (t < PM) {
        int i = row0 + t;
        if (i < N) {
            for (int m = 0; m < NC; ++m) {
                cand [(size_t)i * NCTOT + split * NC + m] = Li[t][m];
                cands[(size_t)i * NCTOT + split * NC + m] = Ls[t][m];
            }
        }
    }
}

// ---------------- Kernel D: pruned exact fp64 rescore + top-k ----------------
__global__ __launch_bounds__(256) void rescore_topk(
    const float* __restrict__ x, const double* __restrict__ w,
    const double* __restrict__ sq, const int* __restrict__ cand,
    const float* __restrict__ cands, int* __restrict__ out, int N, int k)
{
    __shared__ float Ssc[4][NCTOT];
    int lane = threadIdx.x & 63;
    int wid  = threadIdx.x >> 6;
    int i = blockIdx.x * 4 + wid;
    if (i >= N) return;

    size_t base = (size_t)i * NCTOT;
    Ssc[wid][lane] = cands[base + lane];
    if (lane < NCTOT - 64) Ssc[wid][64 + lane] = cands[base + 64 + lane];

    // 9th-smallest via pivot counting: pivots cover all 72 slots
    float p0 = Ssc[wid][lane];
    float p1 = Ssc[wid][64 + (lane & 7)];
    int c0 = 0, c1 = 0;
    for (int m = 0; m < NCTOT; ++m) {
        float s = Ssc[wid][m];
        c0 += (s <= p0); c1 += (s <= p1);
    }
    float best = __builtin_inff();
    if (c0 >= k) best = p0;
    if (c1 >= k && p1 < best) best = p1;
#pragma unroll
    for (int off = 32; off > 0; off >>= 1)
        best = fminf(best, __shfl_xor(best, off, 64));
    float cut = best + RS_MARGIN;

    double aw[8];
#pragma unroll
    for (int c = 0; c < 8; ++c) {
        int d = lane + 64 * c;
        aw[c] = (double)x[(size_t)i * DD + d] * w[d];
    }
    double sqi = sq[i];

    double bs[KOUTMAX];
    int    bj[KOUTMAX];
    for (int r = 0; r < k; ++r) { bs[r] = __builtin_inf(); bj[r] = 0x7fffffff; }

    int pend = -1;                    // wave-uniform pending candidate index j
    for (int m = 0; m <= NCTOT; ++m) {
        int j1cand = -1;
        if (m < NCTOT) {
            if (Ssc[wid][m] > cut) continue;          // wave-uniform skip
            j1cand = cand[base + m];
            if (pend < 0) { pend = j1cand; continue; } // buffer first of a pair
        } else if (pend < 0) {
            break;                                     // nothing left
        }
        int j0 = pend, j1 = j1cand;
        pend = -1;
        const float* q0 = &x[(size_t)j0 * DD + lane];
        const float* q1 = (j1 >= 0) ? &x[(size_t)j1 * DD + lane] : q0;
        float v0[8], v1[8];
#pragma unroll
        for (int c = 0; c < 8; ++c) v0[c] = q0[64 * c];
#pragma unroll
        for (int c = 0; c < 8; ++c) v1[c] = q1[64 * c];
        double d0 = 0.0, d1 = 0.0;
#pragma unroll
        for (int c = 0; c < 8; ++c) d0 = fma(aw[c], (double)v0[c], d0);
#pragma unroll
        for (int c = 0; c < 8; ++c) d1 = fma(aw[c], (double)v1[c], d1);
#pragma unroll
        for (int off = 32; off > 0; off >>= 1) {
            d0 += __shfl_xor(d0, off, 64);
            d1 += __shfl_xor(d1, off, 64);
        }
        double s0 = (sqi - 2.0 * d0) + sq[j0];
        double s1 = (j1 >= 0) ? (sqi - 2.0 * d1) + sq[j1] : __builtin_inf();
#pragma unroll 1
        for (int pick = 0; pick < 2; ++pick) {
            double sv = pick ? s1 : s0;
            int    j  = pick ? j1 : j0;
            if (j < 0) continue;
            if (sv < bs[k - 1] || (sv == bs[k - 1] && j < bj[k - 1])) {
                int pos = k - 1;
                while (pos > 0) {
                    double ps = bs[pos - 1]; int pj = bj[pos - 1];
                    if (!(sv < ps || (sv == ps && j < pj))) break;
                    bs[pos] = ps; bj[pos] = pj;
                    --pos;
                }
                bs[pos] = sv; bj[pos] = j;
            }
        }
    }
    if (lane == 0) {
        for (int r = 0; r < k; ++r) {
            out[(size_t)i * k + r]                 = bj[r];
            out[(size_t)N * k + (size_t)i * k + r] = i;
        }
    }
}

extern "C" void kernel_launch(void* const* d_in, const int* in_sizes, int n_in,
                              void* d_out, int out_size, void* d_ws, size_t ws_size,
                              hipStream_t stream) {
    const float* x = (const float*)d_in[0];
    int N = in_sizes[0] / DD;            // 10000
    int k = out_size / (2 * N);          // 9
    if (k > KOUTMAX) k = KOUTMAX;

    char* ws = (char*)d_ws;
    double*         partial = (double*)ws;                       // 400*512*8 = 1638400 B
    double*         rn      = (double*)(ws + 1638400);           // 4096 B
    double*         w       = (double*)(ws + 1642496);           // 4096 B
    double*         sq      = (double*)(ws + 1646592);           // 80000 B
    float*          sqf     = (float*) (ws + 1726592);           // 40000 B
    unsigned short* xnbf    = (unsigned short*)(ws + 1766592);   // N*512*2 = 10.24 MB
    int*            cand    = (int*)   (ws + 12006592);          // N*72*4 = 2.88 MB
    float*          cands   = (float*) (ws + 14886592);          // N*72*4 = 2.88 MB

    int rpb = (N + NBLKA - 1) / NBLKA;
    hipLaunchKernelGGL(colsum_partial, dim3(NBLKA), dim3(256), 0, stream, x, partial, N, rpb);
    hipLaunchKernelGGL(colnorm_finish, dim3(1), dim3(512), 0, stream, partial, rn, w, NBLKA);
    hipLaunchKernelGGL(row_sq, dim3(N), dim3(256), 0, stream, x, rn, sq, sqf, xnbf, N);

    int ntileM = (N + PM - 1) / PM;      // 79
    int ntileN = (N + PN - 1) / PN;      // 79
    int rows_per_xcd = (ntileM + 7) / 8; // 10
    int nblk = 8 * rows_per_xcd * CSPLIT; // 480 (pad blocks exit early)
    hipLaunchKernelGGL(gemm_prefilter, dim3(nblk), dim3(256), 0, stream,
                       xnbf, sqf, cand, cands, N, ntileM, ntileN);

    hipLaunchKernelGGL(rescore_topk, dim3((N + 3) / 4), dim3(256), 0, stream,
                       x, w, sq, cand, cands, (int*)d_out, N, k);
}